// Round 5
// baseline (439.834 us; speedup 1.0000x reference)
//
#include <hip/hip_runtime.h>
#include <cfloat>
#include <math.h>

#define NPTS   5000
#define BATCH  2
#define DIM    128
#define NBINS  10
#define BINSZ  500
#define TOPK   5
#define ROTCOLS 100   // rotations stored [128, 100]; we use first NBINS/2 = 5

// ---------------- Kernel A: bin assignment + squared norms (fp64 acc) -----
// Stays fp64: a single argmax flip vs the np-f64 reference permutes whole
// bins (catastrophic). f32 margin analysis gives ~3% session risk -- no.
#define KB_PTS 64
#define KB_STR 129
__global__ void k_bins(const float* __restrict__ pts, const float* __restrict__ rot,
                       int* __restrict__ bin_idx, double* __restrict__ na) {
    __shared__ float P[KB_PTS * KB_STR];
    __shared__ float rotL[DIM * 5];
    int tid = threadIdx.x;
    for (int f = tid; f < DIM * 5; f += 256)
        rotL[f] = rot[(f / 5) * ROTCOLS + (f % 5)];

    int p0  = blockIdx.x * KB_PTS;
    int npb = min(KB_PTS, BATCH * NPTS - p0);

    for (int f = tid; f < npb * DIM; f += 256) {
        int r = f >> 7, d = f & 127;
        P[r * KB_STR + d] = pts[(size_t)(p0 + r) * DIM + d];
    }
    __syncthreads();

    int p = tid >> 2;    // point within block
    int s = tid & 3;     // dim quarter
    double acc[5] = {0., 0., 0., 0., 0.};
    double sq = 0.;
    const float* row = &P[p * KB_STR + s * 32];
    for (int j = 0; j < 32; ++j) {
        double v = (double)row[j];
        sq += v * v;
        int d = s * 32 + j;
#pragma unroll
        for (int h = 0; h < 5; ++h) acc[h] += v * (double)rotL[d * 5 + h];
    }
#pragma unroll
    for (int m = 1; m < 4; m <<= 1) {
#pragma unroll
        for (int h = 0; h < 5; ++h) acc[h] += __shfl_xor(acc[h], m, 4);
        sq += __shfl_xor(sq, m, 4);
    }
    if (s == 0 && p < npb) {
        double best = acc[0]; int bc = 0;
#pragma unroll
        for (int c = 1; c < NBINS; ++c) {
            double v = (c < 5) ? acc[c] : -acc[c - 5];
            if (v > best) { best = v; bc = c; }
        }
        bin_idx[p0 + p] = bc;
        na[p0 + p] = sq;
    }
}

// ---------------- Kernel B: stable counting sort (== stable argsort) ------
__global__ void k_sort(const int* __restrict__ bin_idx, int* __restrict__ order) {
    const int b = blockIdx.x;
    const int t = threadIdx.x;               // 256 threads
    const int NPT = (NPTS + 255) / 256;      // 20
    int start = t * NPT;
    int end   = min(NPTS, start + NPT);

    int cnt[NBINS];
#pragma unroll
    for (int c = 0; c < NBINS; ++c) cnt[c] = 0;
    for (int i = start; i < end; ++i) {
        int c = bin_idx[b * NPTS + i];
#pragma unroll
        for (int k = 0; k < NBINS; ++k) cnt[k] += (c == k);
    }

    __shared__ int hist[NBINS * 256];
#pragma unroll
    for (int c = 0; c < NBINS; ++c) hist[c * 256 + t] = cnt[c];
    __syncthreads();

    int base = t * NBINS;
    int s = 0;
#pragma unroll
    for (int k = 0; k < NBINS; ++k) s += hist[base + k];
    __shared__ int scan[256];
    scan[t] = s;
    __syncthreads();
    for (int off = 1; off < 256; off <<= 1) {
        int v = (t >= off) ? scan[t - off] : 0;
        __syncthreads();
        scan[t] += v;
        __syncthreads();
    }
    int run = scan[t] - s;
#pragma unroll
    for (int k = 0; k < NBINS; ++k) { int h = hist[base + k]; hist[base + k] = run; run += h; }
    __syncthreads();

    int ofs[NBINS];
#pragma unroll
    for (int c = 0; c < NBINS; ++c) ofs[c] = hist[c * 256 + t];
    for (int i = start; i < end; ++i) {
        int c = bin_idx[b * NPTS + i];
        int pos = 0;
#pragma unroll
        for (int k = 0; k < NBINS; ++k) {
            if (c == k) pos = ofs[k];
            ofs[k] += (c == k);
        }
        order[b * NPTS + pos] = i;
    }
}

// -- Kernel C: f32 gram rank (top-8) + f64 refine + zero-fill/scatter ------
// Evidence trail:
//  * f64 MFMA (v_mfma_f64_16x16x4f64) abandoned (R0-R2): probe outputs match
//    NO layout family -> instruction effectively unusable on gfx950. Do not
//    revisit without external proof.
//  * R3 k-split cut LDS reads 33% -> ZERO time change => not LDS-bound.
//    VALUBusy 45% == f64 FMA (4cyc) + f32->f64 cvt arithmetic => VALU-work
//    bound on the f64 gram.
//  * This version: rank candidates with an f32 gram (error ~2e-4 abs vs
//    candidate gaps ~0.1-0.5), keep per-row top-8, then recompute those 8 in
//    f64 (same 64+64 halves summation order as R3, which measured absmax
//    0.0) and select exact (key asc, idx asc) top-5. Selection/values are
//    bit-identical to the f64 path unless >=3 simultaneous f32-scale
//    near-ties at the rank-8 boundary (P ~ 1e-5 problem-wide).
//  * Register prefetch / wide candidate state / one-barrier restructures
//    regressed via scratch traffic; all per-thread state static-indexed.
#define RT     16
#define NRT    32
#define CTILE  64
#define RSTRDF 128     // rowPf stride in floats (512B rows; A-reads broadcast)
#define CSTR   132     // colP stride in floats
#define NCT    8
#define ROWQ   (NPTS/4)
#define TOPM   8       // f32 rank depth carried per thread / per row

__launch_bounds__(256, 3)
__global__ void k_chunks(const float* __restrict__ pts, const double* __restrict__ na,
                         const int* __restrict__ order, float* __restrict__ out) {
    __shared__ float  rowPf[RT * RSTRDF];   // 8192 B
    __shared__ float  colP[CTILE * CSTR];   // 33792 B
    __shared__ float  naCf[CTILE];          // 256 B
    __shared__ double naRs[RT];             // 128 B
    __shared__ int    ordR[RT];             // 64 B
    __shared__ double refVal[RT][TOPM];     // 1024 B
    __shared__ int    refIdx[RT][TOPM];     // 512 B   -> ~44 KB, 3 blocks/CU

    int blk   = blockIdx.x;
    int rt    = blk & (NRT - 1);
    int chunk = blk >> 5;          // 0..19
    int b     = chunk / NBINS;
    int c     = chunk % NBINS;
    int tid   = threadIdx.x;
    int row0  = rt * RT;
    int rowCount = min(RT, BINSZ - row0);   // 16, except last tile: 4

    const int*   ordBase = order + b * NPTS + c * BINSZ;
    const float* ptsB    = pts + (size_t)b * NPTS * DIM;

    // stage row points (f32; exact copies of inputs)
    for (int f = tid; f < rowCount * (DIM / 4); f += 256) {
        int r = f >> 5;
        int q = f & 31;
        int g = ordBase[row0 + r];
        float4 v = *(const float4*)(ptsB + (size_t)g * DIM + q * 4);
        *(float4*)(&rowPf[r * RSTRDF + q * 4]) = v;
    }
    if (tid < rowCount) {
        int g = ordBase[row0 + tid];
        ordR[tid] = g;
        naRs[tid] = na[b * NPTS + g];
    }
    __syncthreads();

    int cg  = tid & 15;         // col group: cols cg, cg+16, cg+32, cg+48
    int ks  = (tid >> 4) & 1;   // k-half: dims [64ks, 64ks+64)
    int rg  = tid >> 5;         // 0..7: rows rg, rg+8
    int cgm = tid & 31;         // merge-lane id within half-wave
    const int q0 = ks * 64;

    float naRf0 = (rg     < rowCount) ? (float)naRs[rg]     : 0.f;
    float naRf1 = (rg + 8 < rowCount) ? (float)naRs[rg + 8] : 0.f;

    // f32 ranking state: bottom-8 (clamped squared distance, strict < with
    // in-order arrival == (key asc, idx asc))
    float tv[2][TOPM];
    int   tl[2][TOPM];
#pragma unroll
    for (int ii = 0; ii < 2; ++ii)
#pragma unroll
        for (int k = 0; k < TOPM; ++k) { tv[ii][k] = FLT_MAX; tl[ii][k] = 0x7fffffff; }

    const int totalZ = rowCount * ROWQ;

    for (int ct = 0; ct < NCT; ++ct) {
        int col0T = ct * CTILE;
        int colCount = min(CTILE, BINSZ - col0T);
        __syncthreads();   // prev tile's readers done before restage
        for (int f = tid; f < colCount * (DIM / 4); f += 256) {
            int j = f >> 5;
            int q = f & 31;
            int g = ordBase[col0T + j];
            float4 v = *(const float4*)(ptsB + (size_t)g * DIM + q * 4);
            *(float4*)(&colP[j * CSTR + q * 4]) = v;
        }
        if (tid < colCount) {
            int g = ordBase[col0T + tid];
            naCf[tid] = (float)na[b * NPTS + g];
        }
        __syncthreads();

        // zero-fill slice ct: stores drain during this tile's gram compute
        {
            float4 z = make_float4(0.f, 0.f, 0.f, 0.f);
            int z0 = (ct * totalZ) / NCT, z1 = ((ct + 1) * totalZ) / NCT;
            for (int f = z0 + tid; f < z1; f += 256) {
                int r = f / ROWQ;
                int q = f - r * ROWQ;
                float* outRow = out + ((size_t)b * NPTS + ordR[r]) * NPTS;
                *(float4*)(outRow + 4 * q) = z;
            }
        }

        // f32 gram: rows {rg, rg+8} x cols {cg,+16,+32,+48}, dims [q0,q0+64)
        float acc00 = 0.f, acc01 = 0.f, acc02 = 0.f, acc03 = 0.f;
        float acc10 = 0.f, acc11 = 0.f, acc12 = 0.f, acc13 = 0.f;

        for (int q = 0; q < 64; q += 4) {
            const int qq = q0 + q;
            float4 a0 = *(const float4*)(&rowPf[rg * RSTRDF + qq]);
            float4 a1 = *(const float4*)(&rowPf[(rg + 8) * RSTRDF + qq]);
            float4 f0 = *(const float4*)(&colP[cg * CSTR + qq]);
            float4 f1 = *(const float4*)(&colP[(cg + 16) * CSTR + qq]);
            float4 f2 = *(const float4*)(&colP[(cg + 32) * CSTR + qq]);
            float4 f3 = *(const float4*)(&colP[(cg + 48) * CSTR + qq]);
            acc00 += a0.x * f0.x + a0.y * f0.y + a0.z * f0.z + a0.w * f0.w;
            acc01 += a0.x * f1.x + a0.y * f1.y + a0.z * f1.z + a0.w * f1.w;
            acc02 += a0.x * f2.x + a0.y * f2.y + a0.z * f2.z + a0.w * f2.w;
            acc03 += a0.x * f3.x + a0.y * f3.y + a0.z * f3.z + a0.w * f3.w;
            acc10 += a1.x * f0.x + a1.y * f0.y + a1.z * f0.z + a1.w * f0.w;
            acc11 += a1.x * f1.x + a1.y * f1.y + a1.z * f1.z + a1.w * f1.w;
            acc12 += a1.x * f2.x + a1.y * f2.y + a1.z * f2.z + a1.w * f2.w;
            acc13 += a1.x * f3.x + a1.y * f3.y + a1.z * f3.z + a1.w * f3.w;
        }

        // combine k-halves: partner lane = lane^16 (same cg, same rg)
        acc00 += __shfl_xor(acc00, 16, 64);
        acc01 += __shfl_xor(acc01, 16, 64);
        acc02 += __shfl_xor(acc02, 16, 64);
        acc03 += __shfl_xor(acc03, 16, 64);
        acc10 += __shfl_xor(acc10, 16, 64);
        acc11 += __shfl_xor(acc11, 16, 64);
        acc12 += __shfl_xor(acc12, 16, 64);
        acc13 += __shfl_xor(acc13, 16, 64);

        // ownership: ks=0 -> cols {cg, cg+16}; ks=1 -> {cg+32, cg+48}
        float selA0 = ks ? acc02 : acc00;
        float selA1 = ks ? acc12 : acc10;
        float selB0 = ks ? acc03 : acc01;
        float selB1 = ks ? acc13 : acc11;
        int colA = cg + (ks ? 32 : 0);
        int colB = cg + (ks ? 48 : 16);

        if (colA < colCount) {
            int   cl = col0T + colA;
            float nc = naCf[colA];
            float cv0 = fmaxf(naRf0 + nc - 2.f * selA0, 1e-6f);
            float cv1 = fmaxf(naRf1 + nc - 2.f * selA1, 1e-6f);
            int cl0 = cl, cl1 = cl;
#pragma unroll
            for (int k = 0; k < TOPM; ++k) {   // strict <: equal keeps earlier idx
                bool lt0 = (cv0 < tv[0][k]);
                float ov0 = tv[0][k]; int ol0 = tl[0][k];
                if (lt0) { tv[0][k] = cv0; tl[0][k] = cl0; cv0 = ov0; cl0 = ol0; }
                bool lt1 = (cv1 < tv[1][k]);
                float ov1 = tv[1][k]; int ol1 = tl[1][k];
                if (lt1) { tv[1][k] = cv1; tl[1][k] = cl1; cv1 = ov1; cl1 = ol1; }
            }
        }
        if (colB < colCount) {
            int   cl = col0T + colB;
            float nc = naCf[colB];
            float cv0 = fmaxf(naRf0 + nc - 2.f * selB0, 1e-6f);
            float cv1 = fmaxf(naRf1 + nc - 2.f * selB1, 1e-6f);
            int cl0 = cl, cl1 = cl;
#pragma unroll
            for (int k = 0; k < TOPM; ++k) {
                bool lt0 = (cv0 < tv[0][k]);
                float ov0 = tv[0][k]; int ol0 = tl[0][k];
                if (lt0) { tv[0][k] = cv0; tl[0][k] = cl0; cv0 = ov0; cl0 = ol0; }
                bool lt1 = (cv1 < tv[1][k]);
                float ov1 = tv[1][k]; int ol1 = tl[1][k];
                if (lt1) { tv[1][k] = cv1; tl[1][k] = cl1; cv1 = ov1; cl1 = ol1; }
            }
        }
    }

    // merge across the 32 threads of each half-wave (disjoint col sets,
    // shared row pair) -- (key asc, idx asc) lexicographic, depth 8
#pragma unroll
    for (int m = 1; m < 32; m <<= 1) {
#pragma unroll
        for (int ii = 0; ii < 2; ++ii) {
            float rv[TOPM]; int rl[TOPM];
#pragma unroll
            for (int k = 0; k < TOPM; ++k) {
                rv[k] = __shfl_xor(tv[ii][k], m, 32);
                rl[k] = __shfl_xor(tl[ii][k], m, 32);
            }
#pragma unroll
            for (int k = 0; k < TOPM; ++k) {
                float cv = rv[k]; int cl = rl[k];
#pragma unroll
                for (int s = 0; s < TOPM; ++s) {
                    bool better = (cv < tv[ii][s]) || (cv == tv[ii][s] && cl < tl[ii][s]);
                    float ov = tv[ii][s]; int ol = tl[ii][s];
                    if (better) { tv[ii][s] = cv; tl[ii][s] = cl; cv = ov; cl = ol; }
                }
            }
        }
    }

    // publish per-row top-8 candidate indices for f64 refinement
    if (cgm == 0) {
#pragma unroll
        for (int ii = 0; ii < 2; ++ii) {
            int r = rg + 8 * ii;
#pragma unroll
            for (int k = 0; k < TOPM; ++k) refIdx[r][k] = tl[ii][k];
        }
    }
    __syncthreads();   // refIdx visible; zero-fill stores issued before here

    // f64 refine: 16 rows x 8 cands, 2 threads per dot (64 dims each),
    // summation = 64+64 halves (same order as the R3 f64 path -> identical
    // bits). Candidate vectors gathered from global (L2-hot).
    {
        int u = tid >> 1;        // 0..127
        int h = tid & 1;         // dim half
        int r = u >> 3;          // 0..15
        int j = u & 7;           // candidate slot
        double dotH = 0.;
        int cl = 0, g = 0;
        if (r < rowCount) {
            cl = refIdx[r][j];
            g  = ordBase[cl];
            const float* cp = ptsB + (size_t)g * DIM + h * 64;
            const float* rp = &rowPf[r * RSTRDF + h * 64];
            for (int q = 0; q < 64; q += 4) {
                float4 cv4 = *(const float4*)(cp + q);
                float4 rv4 = *(const float4*)(rp + q);
                dotH += (double)rv4.x * cv4.x + (double)rv4.y * cv4.y +
                        (double)rv4.z * cv4.z + (double)rv4.w * cv4.w;
            }
        }
        double full = dotH + __shfl_xor(dotH, 1, 64);
        if (h == 0 && r < rowCount) {
            double naRv = naRs[r];
            double naCv = na[b * NPTS + g];
            refVal[r][j] = fmax(naRv + naCv - 2. * full, 1e-6);
        }
    }
    __syncthreads();

    // exact top-5 among the 8 f64 candidates; sqrt/exp/scatter
    if (tid < RT && tid < rowCount) {
        double fv[TOPK]; int fl[TOPK];
#pragma unroll
        for (int k = 0; k < TOPK; ++k) { fv[k] = DBL_MAX; fl[k] = 0x7fffffff; }
#pragma unroll
        for (int j = 0; j < TOPM; ++j) {
            double cv = refVal[tid][j];
            int    cl = refIdx[tid][j];
#pragma unroll
            for (int s = 0; s < TOPK; ++s) {   // (key asc, idx asc) total order
                bool better = (cv < fv[s]) || (cv == fv[s] && cl < fl[s]);
                double ov = fv[s]; int ol = fl[s];
                if (better) { fv[s] = cv; fl[s] = cl; cv = ov; cl = ol; }
            }
        }
        int src = ordR[tid];
        float* outRow = out + ((size_t)b * NPTS + src) * NPTS;
#pragma unroll
        for (int k = 0; k < TOPK; ++k) {
            double dist = sqrt(fv[k]);     // fv already clamped
            double dm   = exp(-0.1 * dist);
            int dst = ordBase[fl[k]];      // chunk-local -> global
            outRow[dst] = (float)dm;
        }
    }
}

// ---------------- launch ----------------
extern "C" void kernel_launch(void* const* d_in, const int* in_sizes, int n_in,
                              void* d_out, int out_size, void* d_ws, size_t ws_size,
                              hipStream_t stream) {
    const float* pts = (const float*)d_in[0];   // [2,5000,128]
    const float* rot = (const float*)d_in[1];   // [128,100]
    float* out = (float*)d_out;                 // [2,5000,5000]

    double* na      = (double*)d_ws;                                    // 80000 B
    int*    bin_idx = (int*)((char*)d_ws + 80000);                      // 40000 B
    int*    order   = (int*)((char*)d_ws + 120000);                     // 40000 B

    k_bins<<<(BATCH * NPTS + KB_PTS - 1) / KB_PTS, 256, 0, stream>>>(pts, rot, bin_idx, na);
    k_sort<<<BATCH, 256, 0, stream>>>(bin_idx, order);
    k_chunks<<<BATCH * NBINS * NRT, 256, 0, stream>>>(pts, na, order, out);
}

// Round 6
// 322.365 us; speedup vs baseline: 1.3644x; 1.3644x over previous
//
#include <hip/hip_runtime.h>
#include <cfloat>
#include <math.h>

#define NPTS   5000
#define BATCH  2
#define DIM    128
#define NBINS  10
#define BINSZ  500
#define TOPK   5
#define ROTCOLS 100   // rotations stored [128, 100]; we use first NBINS/2 = 5

// ---------------- Kernel Z: dedicated zero-fill of out ---------------------
// Ablation split (R5): R3's k_chunks embedded 197MB of zero stores in the
// tile loop; every per-tile barrier drains them (implicit vmcnt(0)) and
// their addressing shares the VALU. A pure fill kernel runs at write-BW
// (~6.3TB/s, cf. harness fillBuffer at 6.4TB/s) = ~31us for 200MB, and
// k_chunks' barriers then only wait on staging.
__global__ void k_zero(float4* __restrict__ out) {
    const size_t n = (size_t)BATCH * NPTS * NPTS / 4;   // 12.5M float4
    float4 z = make_float4(0.f, 0.f, 0.f, 0.f);
    for (size_t i = (size_t)blockIdx.x * 256 + threadIdx.x; i < n; i += (size_t)2048 * 256)
        out[i] = z;
}

// ---------------- Kernel A: bin assignment + squared norms (fp64 acc) -----
// Stays fp64: a single argmax flip vs the np-f64 reference permutes whole
// bins (catastrophic).
#define KB_PTS 64
#define KB_STR 129
__global__ void k_bins(const float* __restrict__ pts, const float* __restrict__ rot,
                       int* __restrict__ bin_idx, double* __restrict__ na) {
    __shared__ float P[KB_PTS * KB_STR];
    __shared__ float rotL[DIM * 5];
    int tid = threadIdx.x;
    for (int f = tid; f < DIM * 5; f += 256)
        rotL[f] = rot[(f / 5) * ROTCOLS + (f % 5)];

    int p0  = blockIdx.x * KB_PTS;
    int npb = min(KB_PTS, BATCH * NPTS - p0);

    for (int f = tid; f < npb * DIM; f += 256) {
        int r = f >> 7, d = f & 127;
        P[r * KB_STR + d] = pts[(size_t)(p0 + r) * DIM + d];
    }
    __syncthreads();

    int p = tid >> 2;    // point within block
    int s = tid & 3;     // dim quarter
    double acc[5] = {0., 0., 0., 0., 0.};
    double sq = 0.;
    const float* row = &P[p * KB_STR + s * 32];
    for (int j = 0; j < 32; ++j) {
        double v = (double)row[j];
        sq += v * v;
        int d = s * 32 + j;
#pragma unroll
        for (int h = 0; h < 5; ++h) acc[h] += v * (double)rotL[d * 5 + h];
    }
#pragma unroll
    for (int m = 1; m < 4; m <<= 1) {
#pragma unroll
        for (int h = 0; h < 5; ++h) acc[h] += __shfl_xor(acc[h], m, 4);
        sq += __shfl_xor(sq, m, 4);
    }
    if (s == 0 && p < npb) {
        double best = acc[0]; int bc = 0;
#pragma unroll
        for (int c = 1; c < NBINS; ++c) {
            double v = (c < 5) ? acc[c] : -acc[c - 5];
            if (v > best) { best = v; bc = c; }
        }
        bin_idx[p0 + p] = bc;
        na[p0 + p] = sq;
    }
}

// ---------------- Kernel B: stable counting sort (== stable argsort) ------
__global__ void k_sort(const int* __restrict__ bin_idx, int* __restrict__ order) {
    const int b = blockIdx.x;
    const int t = threadIdx.x;               // 256 threads
    const int NPT = (NPTS + 255) / 256;      // 20
    int start = t * NPT;
    int end   = min(NPTS, start + NPT);

    int cnt[NBINS];
#pragma unroll
    for (int c = 0; c < NBINS; ++c) cnt[c] = 0;
    for (int i = start; i < end; ++i) {
        int c = bin_idx[b * NPTS + i];
#pragma unroll
        for (int k = 0; k < NBINS; ++k) cnt[k] += (c == k);
    }

    __shared__ int hist[NBINS * 256];
#pragma unroll
    for (int c = 0; c < NBINS; ++c) hist[c * 256 + t] = cnt[c];
    __syncthreads();

    int base = t * NBINS;
    int s = 0;
#pragma unroll
    for (int k = 0; k < NBINS; ++k) s += hist[base + k];
    __shared__ int scan[256];
    scan[t] = s;
    __syncthreads();
    for (int off = 1; off < 256; off <<= 1) {
        int v = (t >= off) ? scan[t - off] : 0;
        __syncthreads();
        scan[t] += v;
        __syncthreads();
    }
    int run = scan[t] - s;
#pragma unroll
    for (int k = 0; k < NBINS; ++k) { int h = hist[base + k]; hist[base + k] = run; run += h; }
    __syncthreads();

    int ofs[NBINS];
#pragma unroll
    for (int c = 0; c < NBINS; ++c) ofs[c] = hist[c * 256 + t];
    for (int i = start; i < end; ++i) {
        int c = bin_idx[b * NPTS + i];
        int pos = 0;
#pragma unroll
        for (int k = 0; k < NBINS; ++k) {
            if (c == k) pos = ofs[k];
            ofs[k] += (c == k);
        }
        order[b * NPTS + pos] = i;
    }
}

// -- Kernel C: k-split 2x4 f64 gram + top-5 + scatter (zero-fill removed) --
// Evidence ledger:
//  * f64 MFMA abandoned (R0-R2): probe outputs match NO layout family on
//    gfx950. Do not revisit without external proof.
//  * R3 k-split (-33% LDS reads) = zero time change => not LDS-bound.
//  * R4 f32-gram + 8-wide rank + f64 refine: VALU busy-time UNCHANGED
//    (56us) but duration 2x => gram math is NOT the dominant VALU cost;
//    8-wide candidate state is a documented regression trap. Reverted.
//  * R5 (this): zero-fill moved to k_zero. Everything else == R3 (123us,
//    absmax 0.0). All selection state static-indexed (scratch trap).
#define RT    16
#define NRT   32
#define CTILE 64
#define RSTRD 130      // rowPd stride in doubles (1040 B rows, 16B-aligned)
#define CSTR  132      // colP stride in floats
#define NCT   8

__launch_bounds__(256, 3)
__global__ void k_chunks(const float* __restrict__ pts, const double* __restrict__ na,
                         const int* __restrict__ order, float* __restrict__ out) {
    __shared__ double rowPd[RT * RSTRD];    // 16640 B
    __shared__ float  colP[CTILE * CSTR];   // 33792 B
    __shared__ double naC[CTILE];
    __shared__ double naRs[RT];
    __shared__ int    ordR[RT];             // ~51.1 KB -> 3 blocks/CU

    int blk   = blockIdx.x;
    int rt    = blk & (NRT - 1);
    int chunk = blk >> 5;          // 0..19
    int b     = chunk / NBINS;
    int c     = chunk % NBINS;
    int tid   = threadIdx.x;
    int row0  = rt * RT;
    int rowCount = min(RT, BINSZ - row0);   // 16, except last tile: 4

    const int*   ordBase = order + b * NPTS + c * BINSZ;
    const float* ptsB    = pts + (size_t)b * NPTS * DIM;

    // stage row points as doubles (gathered via order; cvt once per element)
    for (int f = tid; f < rowCount * (DIM / 4); f += 256) {
        int r = f >> 5;
        int q = f & 31;
        int g = ordBase[row0 + r];
        float4 v = *(const float4*)(ptsB + (size_t)g * DIM + q * 4);
        double2 d01; d01.x = (double)v.x; d01.y = (double)v.y;
        double2 d23; d23.x = (double)v.z; d23.y = (double)v.w;
        *(double2*)(&rowPd[r * RSTRD + q * 4 + 0]) = d01;
        *(double2*)(&rowPd[r * RSTRD + q * 4 + 2]) = d23;
    }
    if (tid < rowCount) {
        int g = ordBase[row0 + tid];
        ordR[tid] = g;
        naRs[tid] = na[b * NPTS + g];
    }
    __syncthreads();

    int cg  = tid & 15;         // col group: cols cg, cg+16, cg+32, cg+48
    int ks  = (tid >> 4) & 1;   // k-half: dims [64ks, 64ks+64)
    int rg  = tid >> 5;         // 0..7: rows rg, rg+8
    int cgm = tid & 31;         // merge-lane id within half-wave
    const int q0 = ks * 64;

    double naRr0 = (rg     < rowCount) ? naRs[rg]     : 0.;
    double naRr1 = (rg + 8 < rowCount) ? naRs[rg + 8] : 0.;

    // selection key: clamped squared distance (smaller = better); bottom-5,
    // strict < with in-order arrival == (key asc, idx asc), matches ref.
    double tv[2][TOPK];
    int    tl[2][TOPK];
#pragma unroll
    for (int ii = 0; ii < 2; ++ii)
#pragma unroll
        for (int k = 0; k < TOPK; ++k) { tv[ii][k] = DBL_MAX; tl[ii][k] = 0x7fffffff; }

    for (int ct = 0; ct < NCT; ++ct) {
        int col0T = ct * CTILE;
        int colCount = min(CTILE, BINSZ - col0T);
        __syncthreads();   // prev tile's readers done before restage
        for (int f = tid; f < colCount * (DIM / 4); f += 256) {
            int j = f >> 5;
            int q = f & 31;
            int g = ordBase[col0T + j];
            float4 v = *(const float4*)(ptsB + (size_t)g * DIM + q * 4);
            *(float4*)(&colP[j * CSTR + q * 4]) = v;
        }
        if (tid < colCount) {
            int g = ordBase[col0T + tid];
            naC[tid] = na[b * NPTS + g];
        }
        __syncthreads();

        // gram: rows {rg, rg+8} x cols {cg,+16,+32,+48}, dims [q0, q0+64)
        double acc00 = 0., acc01 = 0., acc02 = 0., acc03 = 0.;
        double acc10 = 0., acc11 = 0., acc12 = 0., acc13 = 0.;

        for (int q = 0; q < 64; q += 4) {
            const int qq = q0 + q;
            double2 a0lo = *(const double2*)(&rowPd[rg * RSTRD + qq + 0]);
            double2 a0hi = *(const double2*)(&rowPd[rg * RSTRD + qq + 2]);
            double2 a1lo = *(const double2*)(&rowPd[(rg + 8) * RSTRD + qq + 0]);
            double2 a1hi = *(const double2*)(&rowPd[(rg + 8) * RSTRD + qq + 2]);
            float4 f0 = *(const float4*)(&colP[cg * CSTR + qq]);
            float4 f1 = *(const float4*)(&colP[(cg + 16) * CSTR + qq]);
            float4 f2 = *(const float4*)(&colP[(cg + 32) * CSTR + qq]);
            float4 f3 = *(const float4*)(&colP[(cg + 48) * CSTR + qq]);
            double b0x = (double)f0.x, b0y = (double)f0.y, b0z = (double)f0.z, b0w = (double)f0.w;
            double b1x = (double)f1.x, b1y = (double)f1.y, b1z = (double)f1.z, b1w = (double)f1.w;
            double b2x = (double)f2.x, b2y = (double)f2.y, b2z = (double)f2.z, b2w = (double)f2.w;
            double b3x = (double)f3.x, b3y = (double)f3.y, b3z = (double)f3.z, b3w = (double)f3.w;
            acc00 += a0lo.x * b0x + a0lo.y * b0y + a0hi.x * b0z + a0hi.y * b0w;
            acc01 += a0lo.x * b1x + a0lo.y * b1y + a0hi.x * b1z + a0hi.y * b1w;
            acc02 += a0lo.x * b2x + a0lo.y * b2y + a0hi.x * b2z + a0hi.y * b2w;
            acc03 += a0lo.x * b3x + a0lo.y * b3y + a0hi.x * b3z + a0hi.y * b3w;
            acc10 += a1lo.x * b0x + a1lo.y * b0y + a1hi.x * b0z + a1hi.y * b0w;
            acc11 += a1lo.x * b1x + a1lo.y * b1y + a1hi.x * b1z + a1hi.y * b1w;
            acc12 += a1lo.x * b2x + a1lo.y * b2y + a1hi.x * b2z + a1hi.y * b2w;
            acc13 += a1lo.x * b3x + a1lo.y * b3y + a1hi.x * b3z + a1hi.y * b3w;
        }

        // combine k-halves: partner lane = lane^16 (same cg, same rg)
        acc00 += __shfl_xor(acc00, 16, 64);
        acc01 += __shfl_xor(acc01, 16, 64);
        acc02 += __shfl_xor(acc02, 16, 64);
        acc03 += __shfl_xor(acc03, 16, 64);
        acc10 += __shfl_xor(acc10, 16, 64);
        acc11 += __shfl_xor(acc11, 16, 64);
        acc12 += __shfl_xor(acc12, 16, 64);
        acc13 += __shfl_xor(acc13, 16, 64);

        // selection ownership: ks=0 -> cols {cg, cg+16}; ks=1 -> {cg+32, cg+48}
        double selA0 = ks ? acc02 : acc00;   // row rg,   first owned col
        double selA1 = ks ? acc12 : acc10;   // row rg+8, first owned col
        double selB0 = ks ? acc03 : acc01;   // row rg,   second owned col
        double selB1 = ks ? acc13 : acc11;   // row rg+8, second owned col
        int colA = cg + (ks ? 32 : 0);
        int colB = cg + (ks ? 48 : 16);

        if (colA < colCount) {
            int    cl = col0T + colA;
            double nc = naC[colA];
            double cv0 = fmax(naRr0 + nc - 2. * selA0, 1e-6);
            double cv1 = fmax(naRr1 + nc - 2. * selA1, 1e-6);
            int cl0 = cl, cl1 = cl;
#pragma unroll
            for (int k = 0; k < TOPK; ++k) {   // strict <: equal keeps earlier idx
                bool lt0 = (cv0 < tv[0][k]);
                double ov0 = tv[0][k]; int ol0 = tl[0][k];
                if (lt0) { tv[0][k] = cv0; tl[0][k] = cl0; cv0 = ov0; cl0 = ol0; }
                bool lt1 = (cv1 < tv[1][k]);
                double ov1 = tv[1][k]; int ol1 = tl[1][k];
                if (lt1) { tv[1][k] = cv1; tl[1][k] = cl1; cv1 = ov1; cl1 = ol1; }
            }
        }
        if (colB < colCount) {
            int    cl = col0T + colB;
            double nc = naC[colB];
            double cv0 = fmax(naRr0 + nc - 2. * selB0, 1e-6);
            double cv1 = fmax(naRr1 + nc - 2. * selB1, 1e-6);
            int cl0 = cl, cl1 = cl;
#pragma unroll
            for (int k = 0; k < TOPK; ++k) {
                bool lt0 = (cv0 < tv[0][k]);
                double ov0 = tv[0][k]; int ol0 = tl[0][k];
                if (lt0) { tv[0][k] = cv0; tl[0][k] = cl0; cv0 = ov0; cl0 = ol0; }
                bool lt1 = (cv1 < tv[1][k]);
                double ov1 = tv[1][k]; int ol1 = tl[1][k];
                if (lt1) { tv[1][k] = cv1; tl[1][k] = cl1; cv1 = ov1; cl1 = ol1; }
            }
        }
    }

    // merge across the 32 threads of each half-wave (all share rows rg, rg+8;
    // they own disjoint col sets covering 0..499)
#pragma unroll
    for (int m = 1; m < 32; m <<= 1) {
#pragma unroll
        for (int ii = 0; ii < 2; ++ii) {
            double rv[TOPK]; int rl[TOPK];
#pragma unroll
            for (int k = 0; k < TOPK; ++k) {
                rv[k] = __shfl_xor(tv[ii][k], m, 32);
                rl[k] = __shfl_xor(tl[ii][k], m, 32);
            }
#pragma unroll
            for (int k = 0; k < TOPK; ++k) {
                double cv = rv[k]; int cl = rl[k];
#pragma unroll
                for (int s = 0; s < TOPK; ++s) {   // (key asc, idx asc) total order
                    bool better = (cv < tv[ii][s]) || (cv == tv[ii][s] && cl < tl[ii][s]);
                    double ov = tv[ii][s]; int ol = tl[ii][s];
                    if (better) { tv[ii][s] = cv; tl[ii][s] = cl; cv = ov; cl = ol; }
                }
            }
        }
    }

    // scatter: lane cgm==0 of each half-wave writes 2 rows x 5 values
    // (out already zeroed by k_zero earlier on this stream)
    if (cgm == 0) {
#pragma unroll
        for (int ii = 0; ii < 2; ++ii) {
            int r = rg + 8 * ii;
            if (r < rowCount) {
                int src = ordR[r];
                float* outRow = out + ((size_t)b * NPTS + src) * NPTS;
#pragma unroll
                for (int k = 0; k < TOPK; ++k) {
                    double dist = sqrt(tv[ii][k]);     // tv already clamped
                    double dm   = exp(-0.1 * dist);
                    int dst = ordBase[tl[ii][k]];      // chunk-local -> global
                    outRow[dst] = (float)dm;
                }
            }
        }
    }
}

// ---------------- launch ----------------
extern "C" void kernel_launch(void* const* d_in, const int* in_sizes, int n_in,
                              void* d_out, int out_size, void* d_ws, size_t ws_size,
                              hipStream_t stream) {
    const float* pts = (const float*)d_in[0];   // [2,5000,128]
    const float* rot = (const float*)d_in[1];   // [128,100]
    float* out = (float*)d_out;                 // [2,5000,5000]

    double* na      = (double*)d_ws;                                    // 80000 B
    int*    bin_idx = (int*)((char*)d_ws + 80000);                      // 40000 B
    int*    order   = (int*)((char*)d_ws + 120000);                     // 40000 B

    k_zero<<<2048, 256, 0, stream>>>((float4*)out);
    k_bins<<<(BATCH * NPTS + KB_PTS - 1) / KB_PTS, 256, 0, stream>>>(pts, rot, bin_idx, na);
    k_sort<<<BATCH, 256, 0, stream>>>(bin_idx, order);
    k_chunks<<<BATCH * NBINS * NRT, 256, 0, stream>>>(pts, na, order, out);
}

// Round 7
// 292.305 us; speedup vs baseline: 1.5047x; 1.1028x over previous
//
#include <hip/hip_runtime.h>
#include <cfloat>
#include <math.h>

#define NPTS   5000
#define BATCH  2
#define DIM    128
#define NBINS  10
#define BINSZ  500
#define TOPK   5
#define ROTCOLS 100   // rotations stored [128, 100]; we use first NBINS/2 = 5

// ---------------- Kernel A: bin assignment + squared norms (fp64 acc) -----
// Stays fp64: a single argmax flip vs the np-f64 reference permutes whole
// bins (catastrophic).
#define KB_PTS 64
#define KB_STR 129
__global__ void k_bins(const float* __restrict__ pts, const float* __restrict__ rot,
                       int* __restrict__ bin_idx, double* __restrict__ na) {
    __shared__ float P[KB_PTS * KB_STR];
    __shared__ float rotL[DIM * 5];
    int tid = threadIdx.x;
    for (int f = tid; f < DIM * 5; f += 256)
        rotL[f] = rot[(f / 5) * ROTCOLS + (f % 5)];

    int p0  = blockIdx.x * KB_PTS;
    int npb = min(KB_PTS, BATCH * NPTS - p0);

    for (int f = tid; f < npb * DIM; f += 256) {
        int r = f >> 7, d = f & 127;
        P[r * KB_STR + d] = pts[(size_t)(p0 + r) * DIM + d];
    }
    __syncthreads();

    int p = tid >> 2;    // point within block
    int s = tid & 3;     // dim quarter
    double acc[5] = {0., 0., 0., 0., 0.};
    double sq = 0.;
    const float* row = &P[p * KB_STR + s * 32];
    for (int j = 0; j < 32; ++j) {
        double v = (double)row[j];
        sq += v * v;
        int d = s * 32 + j;
#pragma unroll
        for (int h = 0; h < 5; ++h) acc[h] += v * (double)rotL[d * 5 + h];
    }
#pragma unroll
    for (int m = 1; m < 4; m <<= 1) {
#pragma unroll
        for (int h = 0; h < 5; ++h) acc[h] += __shfl_xor(acc[h], m, 4);
        sq += __shfl_xor(sq, m, 4);
    }
    if (s == 0 && p < npb) {
        double best = acc[0]; int bc = 0;
#pragma unroll
        for (int c = 1; c < NBINS; ++c) {
            double v = (c < 5) ? acc[c] : -acc[c - 5];
            if (v > best) { best = v; bc = c; }
        }
        bin_idx[p0 + p] = bc;
        na[p0 + p] = sq;
    }
}

// ---------------- Kernel B: stable counting sort (== stable argsort) ------
__global__ void k_sort(const int* __restrict__ bin_idx, int* __restrict__ order) {
    const int b = blockIdx.x;
    const int t = threadIdx.x;               // 256 threads
    const int NPT = (NPTS + 255) / 256;      // 20
    int start = t * NPT;
    int end   = min(NPTS, start + NPT);

    int cnt[NBINS];
#pragma unroll
    for (int c = 0; c < NBINS; ++c) cnt[c] = 0;
    for (int i = start; i < end; ++i) {
        int c = bin_idx[b * NPTS + i];
#pragma unroll
        for (int k = 0; k < NBINS; ++k) cnt[k] += (c == k);
    }

    __shared__ int hist[NBINS * 256];
#pragma unroll
    for (int c = 0; c < NBINS; ++c) hist[c * 256 + t] = cnt[c];
    __syncthreads();

    int base = t * NBINS;
    int s = 0;
#pragma unroll
    for (int k = 0; k < NBINS; ++k) s += hist[base + k];
    __shared__ int scan[256];
    scan[t] = s;
    __syncthreads();
    for (int off = 1; off < 256; off <<= 1) {
        int v = (t >= off) ? scan[t - off] : 0;
        __syncthreads();
        scan[t] += v;
        __syncthreads();
    }
    int run = scan[t] - s;
#pragma unroll
    for (int k = 0; k < NBINS; ++k) { int h = hist[base + k]; hist[base + k] = run; run += h; }
    __syncthreads();

    int ofs[NBINS];
#pragma unroll
    for (int c = 0; c < NBINS; ++c) ofs[c] = hist[c * 256 + t];
    for (int i = start; i < end; ++i) {
        int c = bin_idx[b * NPTS + i];
        int pos = 0;
#pragma unroll
        for (int k = 0; k < NBINS; ++k) {
            if (c == k) pos = ofs[k];
            ofs[k] += (c == k);
        }
        order[b * NPTS + pos] = i;
    }
}

// -- Kernel C: fine-grain (8-row) k-split f64 gram + top-5 + zero/scatter --
// Evidence ledger:
//  * f64 MFMA abandoned (R0-R2): probe outputs match NO layout family on
//    gfx950 -> unusable. Do not revisit without external proof.
//  * R3: -33% LDS reads = zero time change => not LDS-throughput-bound.
//  * R4: f32 gram + 8-wide rank = VALU busy-time unchanged, duration 2x
//    (wide-candidate-state trap). Gram FLOPs are NOT the dominant cost.
//  * R5: zero-fill split to its own kernel = k_chunks UNCHANGED, +28us
//    serial fill => embedded zero-fill is free overlap. Re-embedded here.
//  * Constant across all: VALU busy ~56us, duration ~123us => ~55% stall
//    at 10 waves/CU (640 blocks, occupancy 22%). THIS round: RT 16->8,
//    CTILE 64->32 => 1260 blocks x 25.6KB LDS => 6 blocks/CU capacity,
//    whole grid co-resident (~20 waves/CU), half per-block serial chain.
//  * All selection state static-indexed (scratch trap).
#define RT    8
#define NRT   63       // ceil(500/8); last row-tile has 4 rows
#define CTILE 32
#define RSTRD 130      // rowPd stride in doubles (1040 B rows, 16B-aligned)
#define CSTR  132      // colP stride in floats
#define NCT   16       // 500 cols -> 16 tiles of 32 (last = 20)
#define ROWQ  (NPTS/4)

__launch_bounds__(256, 6)
__global__ void k_chunks(const float* __restrict__ pts, const double* __restrict__ na,
                         const int* __restrict__ order, float* __restrict__ out) {
    __shared__ double rowPd[RT * RSTRD];    // 8320 B
    __shared__ float  colP[CTILE * CSTR];   // 16896 B
    __shared__ double naC[CTILE];           // 256 B
    __shared__ double naRs[RT];             // 64 B
    __shared__ int    ordR[RT];             // 32 B  -> ~25.6 KB, 6 blocks/CU

    int blk   = blockIdx.x;
    int rt    = blk % NRT;
    int chunk = blk / NRT;         // 0..19
    int b     = chunk / NBINS;
    int c     = chunk % NBINS;
    int tid   = threadIdx.x;
    int row0  = rt * RT;
    int rowCount = min(RT, BINSZ - row0);   // 8, except last tile: 4

    const int*   ordBase = order + b * NPTS + c * BINSZ;
    const float* ptsB    = pts + (size_t)b * NPTS * DIM;

    // stage row points as doubles (gathered via order; cvt once per element)
    for (int f = tid; f < rowCount * (DIM / 4); f += 256) {
        int r = f >> 5;
        int q = f & 31;
        int g = ordBase[row0 + r];
        float4 v = *(const float4*)(ptsB + (size_t)g * DIM + q * 4);
        double2 d01; d01.x = (double)v.x; d01.y = (double)v.y;
        double2 d23; d23.x = (double)v.z; d23.y = (double)v.w;
        *(double2*)(&rowPd[r * RSTRD + q * 4 + 0]) = d01;
        *(double2*)(&rowPd[r * RSTRD + q * 4 + 2]) = d23;
    }
    if (tid < rowCount) {
        int g = ordBase[row0 + tid];
        ordR[tid] = g;
        naRs[tid] = na[b * NPTS + g];
    }
    __syncthreads();

    int cg  = tid & 15;         // col within tile: owns col cg (ks=0) / cg+16 (ks=1)
    int ks  = (tid >> 4) & 1;   // k-half: dims [64ks, 64ks+64)
    int rg  = tid >> 5;         // 0..7: row rg
    int cgm = tid & 31;         // lane id within the 32-thread row group
    const int q0 = ks * 64;

    double naRr = (rg < rowCount) ? naRs[rg] : 0.;

    // selection key: clamped squared distance (smaller = better); bottom-5,
    // strict < with in-order arrival == (key asc, idx asc), matches ref.
    double tv[TOPK];
    int    tl[TOPK];
#pragma unroll
    for (int k = 0; k < TOPK; ++k) { tv[k] = DBL_MAX; tl[k] = 0x7fffffff; }

    const int totalZ = rowCount * ROWQ;

    for (int ct = 0; ct < NCT; ++ct) {
        int col0T = ct * CTILE;
        int colCount = min(CTILE, BINSZ - col0T);   // 32, last tile: 20
        __syncthreads();   // prev tile's readers done before restage
        for (int f = tid; f < colCount * (DIM / 4); f += 256) {
            int j = f >> 5;
            int q = f & 31;
            int g = ordBase[col0T + j];
            float4 v = *(const float4*)(ptsB + (size_t)g * DIM + q * 4);
            *(float4*)(&colP[j * CSTR + q * 4]) = v;
        }
        if (tid < colCount) {
            int g = ordBase[col0T + tid];
            naC[tid] = na[b * NPTS + g];
        }
        __syncthreads();

        // zero-fill slice ct: stores drain during this tile's gram compute
        {
            float4 z = make_float4(0.f, 0.f, 0.f, 0.f);
            int z0 = (ct * totalZ) / NCT, z1 = ((ct + 1) * totalZ) / NCT;
            for (int f = z0 + tid; f < z1; f += 256) {
                int r = f / ROWQ;
                int q = f - r * ROWQ;
                float* outRow = out + ((size_t)b * NPTS + ordR[r]) * NPTS;
                *(float4*)(outRow + 4 * q) = z;
            }
        }

        // gram: row rg x cols {cg, cg+16}, dims [q0, q0+64)
        double acc0 = 0., acc1 = 0.;
        for (int q = 0; q < 64; q += 4) {
            const int qq = q0 + q;
            double2 alo = *(const double2*)(&rowPd[rg * RSTRD + qq + 0]);
            double2 ahi = *(const double2*)(&rowPd[rg * RSTRD + qq + 2]);
            float4 f0 = *(const float4*)(&colP[cg * CSTR + qq]);
            float4 f1 = *(const float4*)(&colP[(cg + 16) * CSTR + qq]);
            double b0x = (double)f0.x, b0y = (double)f0.y, b0z = (double)f0.z, b0w = (double)f0.w;
            double b1x = (double)f1.x, b1y = (double)f1.y, b1z = (double)f1.z, b1w = (double)f1.w;
            acc0 += alo.x * b0x + alo.y * b0y + ahi.x * b0z + ahi.y * b0w;
            acc1 += alo.x * b1x + alo.y * b1y + ahi.x * b1z + ahi.y * b1w;
        }

        // combine k-halves: partner lane = lane^16 (same cg, same rg)
        acc0 += __shfl_xor(acc0, 16, 64);
        acc1 += __shfl_xor(acc1, 16, 64);

        // ownership: ks=0 -> col cg; ks=1 -> col cg+16 (one candidate/tile,
        // cols strictly ascending across tiles -> strict < keeps earlier idx)
        double sel = ks ? acc1 : acc0;
        int    col = cg + (ks ? 16 : 0);
        if (col < colCount) {
            int    ci = col0T + col;
            double cv = fmax(naRr + naC[col] - 2. * sel, 1e-6);
#pragma unroll
            for (int k = 0; k < TOPK; ++k) {   // strict <: equal keeps earlier idx
                bool lt = (cv < tv[k]);
                double ov = tv[k]; int ol = tl[k];
                if (lt) { tv[k] = cv; tl[k] = ci; cv = ov; ci = ol; }
            }
        }
    }

    // merge across the 32 threads sharing row rg (disjoint col sets covering
    // 0..499; contiguous half-wave) -- width-32 butterfly, (key asc, idx asc)
#pragma unroll
    for (int m = 1; m < 32; m <<= 1) {
        double rv[TOPK]; int rl[TOPK];
#pragma unroll
        for (int k = 0; k < TOPK; ++k) {
            rv[k] = __shfl_xor(tv[k], m, 32);
            rl[k] = __shfl_xor(tl[k], m, 32);
        }
#pragma unroll
        for (int k = 0; k < TOPK; ++k) {
            double cv = rv[k]; int cl = rl[k];
#pragma unroll
            for (int s = 0; s < TOPK; ++s) {   // (key asc, idx asc) total order
                bool better = (cv < tv[s]) || (cv == tv[s] && cl < tl[s]);
                double ov = tv[s]; int ol = tl[s];
                if (better) { tv[s] = cv; tl[s] = cl; cv = ov; cl = ol; }
            }
        }
    }

    __syncthreads();   // drain last zero slice before value scatter

    // scatter: lane cgm==0 of each row group writes 1 row x 5 values
    if (cgm == 0 && rg < rowCount) {
        int src = ordR[rg];
        float* outRow = out + ((size_t)b * NPTS + src) * NPTS;
#pragma unroll
        for (int k = 0; k < TOPK; ++k) {
            double dist = sqrt(tv[k]);     // tv already clamped
            double dm   = exp(-0.1 * dist);
            int dst = ordBase[tl[k]];      // chunk-local -> global
            outRow[dst] = (float)dm;
        }
    }
}

// ---------------- launch ----------------
extern "C" void kernel_launch(void* const* d_in, const int* in_sizes, int n_in,
                              void* d_out, int out_size, void* d_ws, size_t ws_size,
                              hipStream_t stream) {
    const float* pts = (const float*)d_in[0];   // [2,5000,128]
    const float* rot = (const float*)d_in[1];   // [128,100]
    float* out = (float*)d_out;                 // [2,5000,5000]

    double* na      = (double*)d_ws;                                    // 80000 B
    int*    bin_idx = (int*)((char*)d_ws + 80000);                      // 40000 B
    int*    order   = (int*)((char*)d_ws + 120000);                     // 40000 B

    k_bins<<<(BATCH * NPTS + KB_PTS - 1) / KB_PTS, 256, 0, stream>>>(pts, rot, bin_idx, na);
    k_sort<<<BATCH, 256, 0, stream>>>(bin_idx, order);
    k_chunks<<<BATCH * NBINS * NRT, 256, 0, stream>>>(pts, na, order, out);
}

// Round 8
// 285.688 us; speedup vs baseline: 1.5396x; 1.0232x over previous
//
#include <hip/hip_runtime.h>
#include <cfloat>
#include <math.h>

#define NPTS   5000
#define BATCH  2
#define DIM    128
#define NBINS  10
#define BINSZ  500
#define TOPK   5
#define ROTCOLS 100   // rotations stored [128, 100]; we use first NBINS/2 = 5

// ---------------- Kernel A: bin assignment + squared norms (fp64 acc) -----
// Stays fp64: a single argmax flip vs the np-f64 reference permutes whole
// bins (catastrophic).
#define KB_PTS 64
#define KB_STR 129
__global__ void k_bins(const float* __restrict__ pts, const float* __restrict__ rot,
                       int* __restrict__ bin_idx, double* __restrict__ na) {
    __shared__ float P[KB_PTS * KB_STR];
    __shared__ float rotL[DIM * 5];
    int tid = threadIdx.x;
    for (int f = tid; f < DIM * 5; f += 256)
        rotL[f] = rot[(f / 5) * ROTCOLS + (f % 5)];

    int p0  = blockIdx.x * KB_PTS;
    int npb = min(KB_PTS, BATCH * NPTS - p0);

    for (int f = tid; f < npb * DIM; f += 256) {
        int r = f >> 7, d = f & 127;
        P[r * KB_STR + d] = pts[(size_t)(p0 + r) * DIM + d];
    }
    __syncthreads();

    int p = tid >> 2;    // point within block
    int s = tid & 3;     // dim quarter
    double acc[5] = {0., 0., 0., 0., 0.};
    double sq = 0.;
    const float* row = &P[p * KB_STR + s * 32];
    for (int j = 0; j < 32; ++j) {
        double v = (double)row[j];
        sq += v * v;
        int d = s * 32 + j;
#pragma unroll
        for (int h = 0; h < 5; ++h) acc[h] += v * (double)rotL[d * 5 + h];
    }
#pragma unroll
    for (int m = 1; m < 4; m <<= 1) {
#pragma unroll
        for (int h = 0; h < 5; ++h) acc[h] += __shfl_xor(acc[h], m, 4);
        sq += __shfl_xor(sq, m, 4);
    }
    if (s == 0 && p < npb) {
        double best = acc[0]; int bc = 0;
#pragma unroll
        for (int c = 1; c < NBINS; ++c) {
            double v = (c < 5) ? acc[c] : -acc[c - 5];
            if (v > best) { best = v; bc = c; }
        }
        bin_idx[p0 + p] = bc;
        na[p0 + p] = sq;
    }
}

// ---------------- Kernel B: stable counting sort (== stable argsort) ------
__global__ void k_sort(const int* __restrict__ bin_idx, int* __restrict__ order) {
    const int b = blockIdx.x;
    const int t = threadIdx.x;               // 256 threads
    const int NPT = (NPTS + 255) / 256;      // 20
    int start = t * NPT;
    int end   = min(NPTS, start + NPT);

    int cnt[NBINS];
#pragma unroll
    for (int c = 0; c < NBINS; ++c) cnt[c] = 0;
    for (int i = start; i < end; ++i) {
        int c = bin_idx[b * NPTS + i];
#pragma unroll
        for (int k = 0; k < NBINS; ++k) cnt[k] += (c == k);
    }

    __shared__ int hist[NBINS * 256];
#pragma unroll
    for (int c = 0; c < NBINS; ++c) hist[c * 256 + t] = cnt[c];
    __syncthreads();

    int base = t * NBINS;
    int s = 0;
#pragma unroll
    for (int k = 0; k < NBINS; ++k) s += hist[base + k];
    __shared__ int scan[256];
    scan[t] = s;
    __syncthreads();
    for (int off = 1; off < 256; off <<= 1) {
        int v = (t >= off) ? scan[t - off] : 0;
        __syncthreads();
        scan[t] += v;
        __syncthreads();
    }
    int run = scan[t] - s;
#pragma unroll
    for (int k = 0; k < NBINS; ++k) { int h = hist[base + k]; hist[base + k] = run; run += h; }
    __syncthreads();

    int ofs[NBINS];
#pragma unroll
    for (int c = 0; c < NBINS; ++c) ofs[c] = hist[c * 256 + t];
    for (int i = start; i < end; ++i) {
        int c = bin_idx[b * NPTS + i];
        int pos = 0;
#pragma unroll
        for (int k = 0; k < NBINS; ++k) {
            if (c == k) pos = ofs[k];
            ofs[k] += (c == k);
        }
        order[b * NPTS + pos] = i;
    }
}

// -- Kernel C: k-split 2x4 f64 gram + async-staged tiles + top-5 + zero ----
// Evidence ledger:
//  * f64 MFMA abandoned (R0-R2): probe outputs match NO layout family on
//    gfx950 -> unusable. Do not revisit without external proof.
//  * R3: -33% LDS reads = zero time change => not LDS-throughput-bound.
//  * R4: f32 gram + 8-wide rank: VALU busy unchanged, duration 2x
//    (wide-candidate-state trap). Gram FLOPs are NOT the dominant cost.
//  * R5: zero-fill split out = k_chunks unchanged => embedded zeroing free.
//  * R6: occupancy 22->53% (RT=8/CTILE=32) = duration WORSE (+restage VALU).
//  * R7 (this): stall theory = dependent staging chain (ord load -> addr ->
//    gathered load) drained by vmcnt(0)+barrier each tile. Fix: ordAll
//    cached in LDS once + T14 issue-early/write-late register prefetch of
//    the next tile (STATIC p0..p7 regs -- prior failures were runtime-
//    indexed arrays -> scratch). Gram/selection/merge bit-identical to R3.
#define RT    16
#define NRT   32
#define CTILE 64
#define RSTRD 130      // rowPd stride in doubles (1040 B rows, 16B-aligned)
#define CSTR  132      // colP stride in floats
#define NCT   8
#define ROWQ  (NPTS/4)

// issue next tile's staging loads into static registers (ordAll must be synced)
#define ISSUE_TILE(CT)                                                        \
    {                                                                         \
        int c0_ = (CT) * CTILE;                                               \
        int jb_ = tid >> 5;                                                   \
        int q4_ = (tid & 31) * 4;                                             \
        p0 = *(const float4*)(ptsB + (size_t)ordAll[min(c0_ + jb_ +  0, BINSZ - 1)] * DIM + q4_); \
        p1 = *(const float4*)(ptsB + (size_t)ordAll[min(c0_ + jb_ +  8, BINSZ - 1)] * DIM + q4_); \
        p2 = *(const float4*)(ptsB + (size_t)ordAll[min(c0_ + jb_ + 16, BINSZ - 1)] * DIM + q4_); \
        p3 = *(const float4*)(ptsB + (size_t)ordAll[min(c0_ + jb_ + 24, BINSZ - 1)] * DIM + q4_); \
        p4 = *(const float4*)(ptsB + (size_t)ordAll[min(c0_ + jb_ + 32, BINSZ - 1)] * DIM + q4_); \
        p5 = *(const float4*)(ptsB + (size_t)ordAll[min(c0_ + jb_ + 40, BINSZ - 1)] * DIM + q4_); \
        p6 = *(const float4*)(ptsB + (size_t)ordAll[min(c0_ + jb_ + 48, BINSZ - 1)] * DIM + q4_); \
        p7 = *(const float4*)(ptsB + (size_t)ordAll[min(c0_ + jb_ + 56, BINSZ - 1)] * DIM + q4_); \
        naCp = na[(size_t)b * NPTS + ordAll[min(c0_ + (tid & 63), BINSZ - 1)]]; \
    }

__launch_bounds__(256, 3)
__global__ void k_chunks(const float* __restrict__ pts, const double* __restrict__ na,
                         const int* __restrict__ order, float* __restrict__ out) {
    __shared__ double rowPd[RT * RSTRD];    // 16640 B
    __shared__ float  colP[CTILE * CSTR];   // 33792 B
    __shared__ double naC[CTILE];           // 512 B
    __shared__ double naRs[RT];             // 128 B
    __shared__ int    ordR[RT];             // 64 B
    __shared__ int    ordAll[BINSZ];        // 2000 B -> 53.1 KB, 3 blocks/CU

    int blk   = blockIdx.x;
    int rt    = blk & (NRT - 1);
    int chunk = blk >> 5;          // 0..19
    int b     = chunk / NBINS;
    int c     = chunk % NBINS;
    int tid   = threadIdx.x;
    int row0  = rt * RT;
    int rowCount = min(RT, BINSZ - row0);   // 16, except last tile: 4

    const int*   ordBase = order + b * NPTS + c * BINSZ;
    const float* ptsB    = pts + (size_t)b * NPTS * DIM;

    // cache this chunk's order slice (kills the per-tile dependent ord loads)
    for (int f = tid; f < BINSZ; f += 256) ordAll[f] = ordBase[f];

    // stage row points as doubles (gathered via order; cvt once per element)
    for (int f = tid; f < rowCount * (DIM / 4); f += 256) {
        int r = f >> 5;
        int q = f & 31;
        int g = ordBase[row0 + r];
        float4 v = *(const float4*)(ptsB + (size_t)g * DIM + q * 4);
        double2 d01; d01.x = (double)v.x; d01.y = (double)v.y;
        double2 d23; d23.x = (double)v.z; d23.y = (double)v.w;
        *(double2*)(&rowPd[r * RSTRD + q * 4 + 0]) = d01;
        *(double2*)(&rowPd[r * RSTRD + q * 4 + 2]) = d23;
    }
    if (tid < rowCount) {
        int g = ordBase[row0 + tid];
        ordR[tid] = g;
        naRs[tid] = na[b * NPTS + g];
    }
    __syncthreads();   // ordAll + rows ready

    int cg  = tid & 15;         // col group: cols cg, cg+16, cg+32, cg+48
    int ks  = (tid >> 4) & 1;   // k-half: dims [64ks, 64ks+64)
    int rg  = tid >> 5;         // 0..7: rows rg, rg+8
    int cgm = tid & 31;         // merge-lane id within half-wave
    const int q0 = ks * 64;

    double naRr0 = (rg     < rowCount) ? naRs[rg]     : 0.;
    double naRr1 = (rg + 8 < rowCount) ? naRs[rg + 8] : 0.;

    // selection key: clamped squared distance (smaller = better); bottom-5,
    // strict < with in-order arrival == (key asc, idx asc), matches ref.
    double tv[2][TOPK];
    int    tl[2][TOPK];
#pragma unroll
    for (int ii = 0; ii < 2; ++ii)
#pragma unroll
        for (int k = 0; k < TOPK; ++k) { tv[ii][k] = DBL_MAX; tl[ii][k] = 0x7fffffff; }

    const int totalZ = rowCount * ROWQ;

    // prefetch tile 0 into registers
    float4 p0, p1, p2, p3, p4, p5, p6, p7;
    double naCp;
    ISSUE_TILE(0);

    for (int ct = 0; ct < NCT; ++ct) {
        int col0T = ct * CTILE;
        int colCount = min(CTILE, BINSZ - col0T);
        __syncthreads();   // prev tile's readers done before restage

        // write phase: regs (loaded last iteration) -> LDS
        {
            int jb = tid >> 5;
            int q4 = (tid & 31) * 4;
            *(float4*)(&colP[(jb +  0) * CSTR + q4]) = p0;
            *(float4*)(&colP[(jb +  8) * CSTR + q4]) = p1;
            *(float4*)(&colP[(jb + 16) * CSTR + q4]) = p2;
            *(float4*)(&colP[(jb + 24) * CSTR + q4]) = p3;
            *(float4*)(&colP[(jb + 32) * CSTR + q4]) = p4;
            *(float4*)(&colP[(jb + 40) * CSTR + q4]) = p5;
            *(float4*)(&colP[(jb + 48) * CSTR + q4]) = p6;
            *(float4*)(&colP[(jb + 56) * CSTR + q4]) = p7;
            if (tid < CTILE) naC[tid] = naCp;
        }
        __syncthreads();

        // issue next tile's loads now; they complete under this tile's gram
        if (ct + 1 < NCT) ISSUE_TILE(ct + 1);

        // zero-fill slice ct: stores drain during this tile's gram compute
        {
            float4 z = make_float4(0.f, 0.f, 0.f, 0.f);
            int z0 = (ct * totalZ) / NCT, z1 = ((ct + 1) * totalZ) / NCT;
            for (int f = z0 + tid; f < z1; f += 256) {
                int r = f / ROWQ;
                int q = f - r * ROWQ;
                float* outRow = out + ((size_t)b * NPTS + ordR[r]) * NPTS;
                *(float4*)(outRow + 4 * q) = z;
            }
        }

        // gram: rows {rg, rg+8} x cols {cg,+16,+32,+48}, dims [q0, q0+64)
        double acc00 = 0., acc01 = 0., acc02 = 0., acc03 = 0.;
        double acc10 = 0., acc11 = 0., acc12 = 0., acc13 = 0.;

        for (int q = 0; q < 64; q += 4) {
            const int qq = q0 + q;
            double2 a0lo = *(const double2*)(&rowPd[rg * RSTRD + qq + 0]);
            double2 a0hi = *(const double2*)(&rowPd[rg * RSTRD + qq + 2]);
            double2 a1lo = *(const double2*)(&rowPd[(rg + 8) * RSTRD + qq + 0]);
            double2 a1hi = *(const double2*)(&rowPd[(rg + 8) * RSTRD + qq + 2]);
            float4 f0 = *(const float4*)(&colP[cg * CSTR + qq]);
            float4 f1 = *(const float4*)(&colP[(cg + 16) * CSTR + qq]);
            float4 f2 = *(const float4*)(&colP[(cg + 32) * CSTR + qq]);
            float4 f3 = *(const float4*)(&colP[(cg + 48) * CSTR + qq]);
            double b0x = (double)f0.x, b0y = (double)f0.y, b0z = (double)f0.z, b0w = (double)f0.w;
            double b1x = (double)f1.x, b1y = (double)f1.y, b1z = (double)f1.z, b1w = (double)f1.w;
            double b2x = (double)f2.x, b2y = (double)f2.y, b2z = (double)f2.z, b2w = (double)f2.w;
            double b3x = (double)f3.x, b3y = (double)f3.y, b3z = (double)f3.z, b3w = (double)f3.w;
            acc00 += a0lo.x * b0x + a0lo.y * b0y + a0hi.x * b0z + a0hi.y * b0w;
            acc01 += a0lo.x * b1x + a0lo.y * b1y + a0hi.x * b1z + a0hi.y * b1w;
            acc02 += a0lo.x * b2x + a0lo.y * b2y + a0hi.x * b2z + a0hi.y * b2w;
            acc03 += a0lo.x * b3x + a0lo.y * b3y + a0hi.x * b3z + a0hi.y * b3w;
            acc10 += a1lo.x * b0x + a1lo.y * b0y + a1hi.x * b0z + a1hi.y * b0w;
            acc11 += a1lo.x * b1x + a1lo.y * b1y + a1hi.x * b1z + a1hi.y * b1w;
            acc12 += a1lo.x * b2x + a1lo.y * b2y + a1hi.x * b2z + a1hi.y * b2w;
            acc13 += a1lo.x * b3x + a1lo.y * b3y + a1hi.x * b3z + a1hi.y * b3w;
        }

        // combine k-halves: partner lane = lane^16 (same cg, same rg)
        acc00 += __shfl_xor(acc00, 16, 64);
        acc01 += __shfl_xor(acc01, 16, 64);
        acc02 += __shfl_xor(acc02, 16, 64);
        acc03 += __shfl_xor(acc03, 16, 64);
        acc10 += __shfl_xor(acc10, 16, 64);
        acc11 += __shfl_xor(acc11, 16, 64);
        acc12 += __shfl_xor(acc12, 16, 64);
        acc13 += __shfl_xor(acc13, 16, 64);

        // selection ownership: ks=0 -> cols {cg, cg+16}; ks=1 -> {cg+32, cg+48}
        double selA0 = ks ? acc02 : acc00;   // row rg,   first owned col
        double selA1 = ks ? acc12 : acc10;   // row rg+8, first owned col
        double selB0 = ks ? acc03 : acc01;   // row rg,   second owned col
        double selB1 = ks ? acc13 : acc11;   // row rg+8, second owned col
        int colA = cg + (ks ? 32 : 0);
        int colB = cg + (ks ? 48 : 16);

        if (colA < colCount) {
            int    cl = col0T + colA;
            double nc = naC[colA];
            double cv0 = fmax(naRr0 + nc - 2. * selA0, 1e-6);
            double cv1 = fmax(naRr1 + nc - 2. * selA1, 1e-6);
            int cl0 = cl, cl1 = cl;
#pragma unroll
            for (int k = 0; k < TOPK; ++k) {   // strict <: equal keeps earlier idx
                bool lt0 = (cv0 < tv[0][k]);
                double ov0 = tv[0][k]; int ol0 = tl[0][k];
                if (lt0) { tv[0][k] = cv0; tl[0][k] = cl0; cv0 = ov0; cl0 = ol0; }
                bool lt1 = (cv1 < tv[1][k]);
                double ov1 = tv[1][k]; int ol1 = tl[1][k];
                if (lt1) { tv[1][k] = cv1; tl[1][k] = cl1; cv1 = ov1; cl1 = ol1; }
            }
        }
        if (colB < colCount) {
            int    cl = col0T + colB;
            double nc = naC[colB];
            double cv0 = fmax(naRr0 + nc - 2. * selB0, 1e-6);
            double cv1 = fmax(naRr1 + nc - 2. * selB1, 1e-6);
            int cl0 = cl, cl1 = cl;
#pragma unroll
            for (int k = 0; k < TOPK; ++k) {
                bool lt0 = (cv0 < tv[0][k]);
                double ov0 = tv[0][k]; int ol0 = tl[0][k];
                if (lt0) { tv[0][k] = cv0; tl[0][k] = cl0; cv0 = ov0; cl0 = ol0; }
                bool lt1 = (cv1 < tv[1][k]);
                double ov1 = tv[1][k]; int ol1 = tl[1][k];
                if (lt1) { tv[1][k] = cv1; tl[1][k] = cl1; cv1 = ov1; cl1 = ol1; }
            }
        }
    }

    // merge across the 32 threads of each half-wave (all share rows rg, rg+8;
    // they own disjoint col sets covering 0..499)
#pragma unroll
    for (int m = 1; m < 32; m <<= 1) {
#pragma unroll
        for (int ii = 0; ii < 2; ++ii) {
            double rv[TOPK]; int rl[TOPK];
#pragma unroll
            for (int k = 0; k < TOPK; ++k) {
                rv[k] = __shfl_xor(tv[ii][k], m, 32);
                rl[k] = __shfl_xor(tl[ii][k], m, 32);
            }
#pragma unroll
            for (int k = 0; k < TOPK; ++k) {
                double cv = rv[k]; int cl = rl[k];
#pragma unroll
                for (int s = 0; s < TOPK; ++s) {   // (key asc, idx asc) total order
                    bool better = (cv < tv[ii][s]) || (cv == tv[ii][s] && cl < tl[ii][s]);
                    double ov = tv[ii][s]; int ol = tl[ii][s];
                    if (better) { tv[ii][s] = cv; tl[ii][s] = cl; cv = ov; cl = ol; }
                }
            }
        }
    }

    __syncthreads();   // drain last zero slice before value scatter

    // scatter: lane cgm==0 of each half-wave writes 2 rows x 5 values
    if (cgm == 0) {
#pragma unroll
        for (int ii = 0; ii < 2; ++ii) {
            int r = rg + 8 * ii;
            if (r < rowCount) {
                int src = ordR[r];
                float* outRow = out + ((size_t)b * NPTS + src) * NPTS;
#pragma unroll
                for (int k = 0; k < TOPK; ++k) {
                    double dist = sqrt(tv[ii][k]);     // tv already clamped
                    double dm   = exp(-0.1 * dist);
                    int dst = ordAll[tl[ii][k]];       // chunk-local -> global
                    outRow[dst] = (float)dm;
                }
            }
        }
    }
}

// ---------------- launch ----------------
extern "C" void kernel_launch(void* const* d_in, const int* in_sizes, int n_in,
                              void* d_out, int out_size, void* d_ws, size_t ws_size,
                              hipStream_t stream) {
    const float* pts = (const float*)d_in[0];   // [2,5000,128]
    const float* rot = (const float*)d_in[1];   // [128,100]
    float* out = (float*)d_out;                 // [2,5000,5000]

    double* na      = (double*)d_ws;                                    // 80000 B
    int*    bin_idx = (int*)((char*)d_ws + 80000);                      // 40000 B
    int*    order   = (int*)((char*)d_ws + 120000);                     // 40000 B

    k_bins<<<(BATCH * NPTS + KB_PTS - 1) / KB_PTS, 256, 0, stream>>>(pts, rot, bin_idx, na);
    k_sort<<<BATCH, 256, 0, stream>>>(bin_idx, order);
    k_chunks<<<BATCH * NBINS * NRT, 256, 0, stream>>>(pts, na, order, out);
}